// Round 1
// 344.258 us; speedup vs baseline: 1.0757x; 1.0757x over previous
//
#include <hip/hip_runtime.h>
#include <hip/hip_bf16.h>

// Problem constants
#define BB_   8
#define DIM_  512
#define LIN_  4096
#define LOUT_ 8192

typedef __attribute__((ext_vector_type(8))) __bf16 bf16x8;
typedef __attribute__((ext_vector_type(4))) float  f32x4;
typedef __attribute__((ext_vector_type(8))) unsigned short u16x8;

__device__ __forceinline__ float bf2f(unsigned short u) {
  union { unsigned int i; float f; } x;
  x.i = ((unsigned int)u) << 16;
  return x.f;
}

// RNE float->bf16 (same as __float2bfloat16 for finite values)
__device__ __forceinline__ unsigned short f2bf(float f) {
  unsigned int u = __float_as_uint(f);
  return (unsigned short)((u + 0x7fffu + ((u >> 16) & 1u)) >> 16);
}

// async global->LDS, 16B per lane; LDS dest = wave-uniform base + lane*16
__device__ __forceinline__ void gload16(const void* g, void* l) {
  __builtin_amdgcn_global_load_lds(
      (__attribute__((address_space(1))) void*)(g),
      (__attribute__((address_space(3))) void*)(l), 16, 0, 0);
}

// ---------------------------------------------------------------------------
// 1) k_prep — heterogeneous grid, 4416 blocks:
//    [0,192):    Mst[kk*512+e][i] = sum_d proj_w[e,d]*conv_w[d,i,kk]  (bf16)
//                64x64 tile per block (kk = bx>>6), 4x4 regs, float4 LDS reads
//    [192,320):  Pcb[e] = sum_d proj_w[e,d]*conv_b[d]
//    [320,4416): Xbt[b][l][d] = bf16(x[b][d][l])   (transpose for GEMM staging)
__global__ __launch_bounds__(256) void k_prep(const float* __restrict__ proj_w,
                                              const float* __restrict__ conv_w,
                                              const float* __restrict__ conv_b,
                                              const float* __restrict__ x,
                                              unsigned short* __restrict__ Mst,
                                              float* __restrict__ Pcb,
                                              unsigned short* __restrict__ Xbt) {
  __shared__ __align__(16) float sm[4160];
  const int bx  = blockIdx.x;
  const int tid = threadIdx.x;

  if (bx < 192) {
    // ---- Mst tile ----
    float* Pt = sm;           // [16][68] : Pt[dl][e]   (stride 68 keeps rows 16B-aligned)
    float* Wt = sm + 1088;    // [16][68] : Wt[dl][i]
    const int kk = bx >> 6;
    const int t6 = bx & 63;
    const int et = (t6 >> 3) << 6;
    const int it = (t6 & 7) << 6;
    const int tx = tid & 15, ty = tid >> 4;
    const int le = tid & 63, lg = tid >> 6;
    float acc[4][4] = {};
    for (int d0 = 0; d0 < DIM_; d0 += 16) {
      {
        const float4 v = *(const float4*)&proj_w[(size_t)(et + le) * DIM_ + d0 + lg * 4];
        Pt[(lg * 4 + 0) * 68 + le] = v.x;
        Pt[(lg * 4 + 1) * 68 + le] = v.y;
        Pt[(lg * 4 + 2) * 68 + le] = v.z;
        Pt[(lg * 4 + 3) * 68 + le] = v.w;
      }
#pragma unroll
      for (int r = 0; r < 4; ++r) {
        const int dl = r * 4 + lg;
        Wt[dl * 68 + le] = conv_w[(size_t)(d0 + dl) * (DIM_ * 3) + (it + le) * 3 + kk];
      }
      __syncthreads();
#pragma unroll
      for (int dl = 0; dl < 16; ++dl) {
        const float4 pv = *(const float4*)&Pt[dl * 68 + ty * 4];
        const float4 wv = *(const float4*)&Wt[dl * 68 + tx * 4];
        const float pa[4] = {pv.x, pv.y, pv.z, pv.w};
        const float wa[4] = {wv.x, wv.y, wv.z, wv.w};
#pragma unroll
        for (int a = 0; a < 4; ++a)
#pragma unroll
          for (int b = 0; b < 4; ++b) acc[a][b] += pa[a] * wa[b];
      }
      __syncthreads();
    }
#pragma unroll
    for (int a = 0; a < 4; ++a) {
      uint2 pk;
      pk.x = (unsigned int)f2bf(acc[a][0]) | ((unsigned int)f2bf(acc[a][1]) << 16);
      pk.y = (unsigned int)f2bf(acc[a][2]) | ((unsigned int)f2bf(acc[a][3]) << 16);
      *(uint2*)&Mst[(size_t)(kk * DIM_ + et + ty * 4 + a) * DIM_ + it + tx * 4] = pk;
    }
  } else if (bx < 320) {
    // ---- Pcb ----
    const int idx = bx - 192;
    const int e = idx * 4 + (tid >> 6);
    const int j = tid & 63;
    float s = 0.f;
#pragma unroll
    for (int d = j; d < DIM_; d += 64) s += proj_w[(size_t)e * DIM_ + d] * conv_b[d];
#pragma unroll
    for (int off = 32; off > 0; off >>= 1) s += __shfl_down(s, off, 64);
    if (j == 0) Pcb[e] = s;
  } else {
    // ---- transpose x -> Xbt (64d x 64l tile per block, LDS stride 65) ----
    const int bc = bx - 320;
    const int bb = bc >> 9;
    const int dt = ((bc >> 6) & 7) << 6;
    const int lt = (bc & 63) << 6;
    const int lr  = tid >> 4;
    const int lc4 = (tid & 15) << 2;
#pragma unroll
    for (int r = 0; r < 4; ++r) {
      const int d = r * 16 + lr;
      const float4 v = *(const float4*)&x[((size_t)(bb * DIM_ + dt + d) << 12) + lt + lc4];
      float* row = sm + d * 65 + lc4;
      row[0] = v.x; row[1] = v.y; row[2] = v.z; row[3] = v.w;
    }
    __syncthreads();
#pragma unroll
    for (int rr = 0; rr < 2; ++rr) {
      const int flat = rr * 256 + tid;
      const int l  = flat >> 3;
      const int d8 = (flat & 7) << 3;
      unsigned int w[4];
#pragma unroll
      for (int p = 0; p < 4; ++p) {
        const float f0 = sm[(d8 + 2 * p + 0) * 65 + l];
        const float f1 = sm[(d8 + 2 * p + 1) * 65 + l];
        w[p] = (unsigned int)f2bf(f0) | ((unsigned int)f2bf(f1) << 16);
      }
      uint4 pk; pk.x = w[0]; pk.y = w[1]; pk.z = w[2]; pk.w = w[3];
      *(uint4*)&Xbt[((size_t)(bb * LIN_ + lt + l) << 9) + dt + d8] = pk;
    }
  }
}

// ---------------------------------------------------------------------------
// 2) k_gemm — flattened GEMM: C[1536][8*4096] = Mst[1536][512] * Xbt^T
//    256x256 tile, BK=32, 8 waves (2Mx4N, 128x64 per wave), 16x16x32 bf16 MFMA.
//    LDS: 4-deep ring of (A 16KB + B 16KB) = 128KB; staging 3 K-tiles ahead via
//    global_load_lds; counted s_waitcnt vmcnt(12) — never drained mid-loop;
//    raw s_barrier (no __syncthreads -> no vmcnt(0) drain).
//    LDS layout: row-major [256][64B], 16B slot = chunk ^ ((row>>1)&3) XOR
//    swizzle on BOTH the gload source address and the ds_read address.
__global__ __launch_bounds__(512, 2) void k_gemm(const unsigned short* __restrict__ Xbt,
                                                 const unsigned short* __restrict__ Mst,
                                                 const float* __restrict__ Pcb,
                                                 unsigned short* __restrict__ U) {
  __shared__ __align__(16) char lds[131072];
  const int tid = threadIdx.x;
  const int bid = blockIdx.x;
  // XCD-bijective swizzle (768 = 8*96), N-major so one XCD's 16 B-panels = 4MB = its L2
  const int wgs   = (bid & 7) * 96 + (bid >> 3);
  const int ntile = wgs / 6;
  const int mtile = wgs - ntile * 6;
  const int bb = ntile >> 4;
  const int l0 = (ntile & 15) << 8;
  const int m0 = mtile << 8;

  // staging geometry: round r covers rows r*128+srow; slot = tid&3 holds chunk slot^((row>>1)&3)
  const int srow   = tid >> 2;
  const int schunk = (tid & 3) ^ ((srow >> 1) & 3);
  const unsigned short* Ag = Mst + (size_t)(m0 + srow) * 512 + schunk * 8;
  const unsigned short* Bg = Xbt + ((size_t)(bb * LIN_ + l0 + srow) << 9) + schunk * 8;
  char* ldsw = lds + (tid >> 6) * 1024;  // wave-uniform LDS base within a round

#define STAGE_(kt_, buf_)                          \
  do {                                             \
    const unsigned short* ga_ = Ag + (kt_) * 32;   \
    const unsigned short* gb_ = Bg + (kt_) * 32;   \
    char* la_ = ldsw + (buf_) * 32768;             \
    gload16(ga_,         la_);                     \
    gload16(ga_ + 65536, la_ + 8192);              \
    gload16(gb_,         la_ + 16384);             \
    gload16(gb_ + 65536, la_ + 24576);             \
  } while (0)

  const int lane = tid & 63;
  const int wave = tid >> 6;
  const int wm = wave >> 2;            // 0..1 : M half
  const int wn = wave & 3;             // 0..3 : N quarter
  const int lrow = lane & 15;
  const int lc   = lane >> 4;          // k-chunk 0..3
  const int aslot = lc ^ ((lrow >> 1) & 3);
  const char* ldsA0 = lds + ((wm * 128 + lrow) * 64 + aslot * 16);
  const char* ldsB0 = lds + (16384 + (wn * 64 + lrow) * 64 + aslot * 16);

  f32x4 acc[8][4] = {};

  STAGE_(0, 0); STAGE_(1, 1); STAGE_(2, 2);

#pragma unroll 4
  for (int kt = 0; kt < 16; ++kt) {
    if (kt < 13) STAGE_(kt + 3, (kt + 3) & 3);
    if (kt < 13)       asm volatile("s_waitcnt vmcnt(12)" ::: "memory");
    else if (kt == 13) asm volatile("s_waitcnt vmcnt(8)" ::: "memory");
    else if (kt == 14) asm volatile("s_waitcnt vmcnt(4)" ::: "memory");
    else               asm volatile("s_waitcnt vmcnt(0)" ::: "memory");
    __builtin_amdgcn_s_barrier();
    __builtin_amdgcn_sched_barrier(0);

    const int bo = (kt & 3) * 32768;
    bf16x8 af[8], bfr[4];
#pragma unroll
    for (int mt = 0; mt < 8; ++mt) af[mt] = *(const bf16x8*)(ldsA0 + bo + mt * 1024);
#pragma unroll
    for (int nt = 0; nt < 4; ++nt) bfr[nt] = *(const bf16x8*)(ldsB0 + bo + nt * 1024);
#pragma unroll
    for (int mt = 0; mt < 8; ++mt)
#pragma unroll
      for (int nt = 0; nt < 4; ++nt)
        // swapped operands: D[l][e] so 4 consecutive l per lane -> 8B packed stores
        acc[mt][nt] = __builtin_amdgcn_mfma_f32_16x16x32_bf16(bfr[nt], af[mt],
                                                              acc[mt][nt], 0, 0, 0);
    asm volatile("s_waitcnt lgkmcnt(0)" ::: "memory");
    __builtin_amdgcn_sched_barrier(0);
    __builtin_amdgcn_s_barrier();
  }
#undef STAGE_

  // epilogue: D row = l (quad*4+reg), D col = e (lane&15)
  const int es0 = m0 + wm * 128 + lrow;
  const int lq  = l0 + wn * 64 + (lc << 2);
#pragma unroll
  for (int mt = 0; mt < 8; ++mt) {
    const int es = es0 + mt * 16;
    const int kk = es >> 9;
    const int e  = es & 511;
    const float bias = (kk < 2) ? Pcb[e] : 0.f;   // bias exactly once across planes
    unsigned short* urow = U + (((size_t)((kk * 8 + bb) * 512 + e)) << 12) + lq;
#pragma unroll
    for (int nt = 0; nt < 4; ++nt) {
      uint2 pk;
      pk.x = (unsigned int)f2bf(acc[mt][nt][0] + bias) |
             ((unsigned int)f2bf(acc[mt][nt][1] + bias) << 16);
      pk.y = (unsigned int)f2bf(acc[mt][nt][2] + bias) |
             ((unsigned int)f2bf(acc[mt][nt][3] + bias) << 16);
      *(uint2*)(urow + nt * 16) = pk;
    }
  }
}

// ---------------------------------------------------------------------------
// 3) k_aa: AA filter + proj bias, barrier-free, 16B loads. (unchanged)
//    u_even(l) = U1[l];  u_odd(l) = U0[l] + U2[l+1] (zero-pad outside [0,4096))
//    out[2l+p] = 17-tap AA over u + proj_b[e]
__global__ __launch_bounds__(256) void k_aa(const __hip_bfloat16* __restrict__ U,
                                            const float* __restrict__ aa,
                                            const float* __restrict__ proj_b,
                                            float* __restrict__ out) {
  const int b  = blockIdx.x >> 9;
  const int e  = blockIdx.x & 511;
  const int l0 = blockIdx.y << 11;
  const int tid = threadIdx.x;
  const int lt = l0 + 8 * tid;
  const unsigned short* q0 = (const unsigned short*)(U + (size_t)((0 * 8 + b) * 512 + e) * 4096);
  const unsigned short* q1 = (const unsigned short*)(U + (size_t)((1 * 8 + b) * 512 + e) * 4096);
  const unsigned short* q2 = (const unsigned short*)(U + (size_t)((2 * 8 + b) * 512 + e) * 4096);

  float E[17], O[16];
  if (lt >= 8 && lt + 16 <= 4096) {
    const int base = lt - 8;
    unsigned short r1[24], r0[24], r2[24];
#pragma unroll
    for (int c = 0; c < 3; ++c) {
      const u16x8 a = *(const u16x8*)(q1 + base + 8 * c);
      const u16x8 d = *(const u16x8*)(q0 + base + 8 * c);
      const u16x8 g = *(const u16x8*)(q2 + base + 8 * c);
#pragma unroll
      for (int j = 0; j < 8; ++j) {
        r1[8 * c + j] = a[j]; r0[8 * c + j] = d[j]; r2[8 * c + j] = g[j];
      }
    }
#pragma unroll
    for (int j = 0; j < 17; ++j) E[j] = bf2f(r1[4 + j]);
#pragma unroll
    for (int j = 0; j < 16; ++j) O[j] = bf2f(r0[4 + j]) + bf2f(r2[5 + j]);
  } else {
#pragma unroll
    for (int j = 0; j < 17; ++j) {
      const int l = lt - 4 + j;
      E[j] = (l >= 0 && l < 4096) ? bf2f(q1[l]) : 0.f;
    }
#pragma unroll
    for (int j = 0; j < 16; ++j) {
      const int l = lt - 4 + j;
      float v = 0.f;
      if (l >= 0 && l < 4096) {
        v = bf2f(q0[l]);
        if (l + 1 < 4096) v += bf2f(q2[l + 1]);
      }
      O[j] = v;
    }
  }

  float sa[17];
#pragma unroll
  for (int j = 0; j < 17; ++j) sa[j] = aa[j];
  const float pb = proj_b[e];
  float res[16];
#pragma unroll
  for (int t = 0; t < 8; ++t) {
    float se = 0.f, so = 0.f;
#pragma unroll
    for (int q = 0; q <= 8; ++q) {
      se += sa[2 * q] * E[t + q];
      so += sa[2 * q] * O[t + q];
    }
#pragma unroll
    for (int q = 0; q < 8; ++q) {
      se += sa[2 * q + 1] * O[t + q];
      so += sa[2 * q + 1] * E[t + q + 1];
    }
    res[2 * t]     = se + pb;
    res[2 * t + 1] = so + pb;
  }
  float* orow = out + (size_t)(b * 512 + e) * 8192 + 2 * lt;
#pragma unroll
  for (int c = 0; c < 4; ++c)
    *(float4*)(orow + 4 * c) = *(const float4*)&res[4 * c];
}

// ---------------------------------------------------------------------------
extern "C" void kernel_launch(void* const* d_in, const int* in_sizes, int n_in,
                              void* d_out, int out_size, void* d_ws, size_t ws_size,
                              hipStream_t stream) {
  const float* x      = (const float*)d_in[0];
  const float* conv_w = (const float*)d_in[1];
  const float* conv_b = (const float*)d_in[2];
  const float* aa     = (const float*)d_in[3];
  const float* proj_w = (const float*)d_in[4];
  const float* proj_b = (const float*)d_in[5];
  float* out = (float*)d_out;

  char* ws = (char*)d_ws;
  unsigned short* Mst = (unsigned short*)ws;              //  1,572,864 B
  float*          Pcb = (float*)(ws + 1572864);           //      2,048 B
  unsigned short* Xbt = (unsigned short*)(ws + 1574912);  // 33,554,432 B
  unsigned short* U   = (unsigned short*)(ws + 35129344); // 100,663,296 B (tot 135.8MB)

  k_prep<<<dim3(4416, 1, 1), 256, 0, stream>>>(proj_w, conv_w, conv_b, x, Mst, Pcb, Xbt);
  k_gemm<<<dim3(768, 1, 1), 512, 0, stream>>>(Xbt, Mst, Pcb, U);
  k_aa<<<dim3(4096, 2), 256, 0, stream>>>((const __hip_bfloat16*)U, aa, proj_b, out);
}

// Round 2
// 321.896 us; speedup vs baseline: 1.1504x; 1.0695x over previous
//
#include <hip/hip_runtime.h>
#include <hip/hip_bf16.h>

// Problem constants
#define BB_   8
#define DIM_  512
#define LIN_  4096
#define LOUT_ 8192

typedef __attribute__((ext_vector_type(8))) __bf16 bf16x8;
typedef __attribute__((ext_vector_type(4))) float  f32x4;
typedef __attribute__((ext_vector_type(8))) unsigned short u16x8;

__device__ __forceinline__ float bf2f(unsigned short u) {
  union { unsigned int i; float f; } x;
  x.i = ((unsigned int)u) << 16;
  return x.f;
}

// RNE float->bf16
__device__ __forceinline__ unsigned short f2bf(float f) {
  unsigned int u = __float_as_uint(f);
  return (unsigned short)((u + 0x7fffu + ((u >> 16) & 1u)) >> 16);
}

// async global->LDS, 16B per lane; LDS dest = wave-uniform base + lane*16
__device__ __forceinline__ void gload16(const void* g, void* l) {
  __builtin_amdgcn_global_load_lds(
      (__attribute__((address_space(1))) void*)(g),
      (__attribute__((address_space(3))) void*)(l), 16, 0, 0);
}

// ---------------------------------------------------------------------------
// 1) k_prep — heterogeneous grid, 4416 blocks (unchanged from prev round):
//    [0,192):    Mst[kk*512+e][i] = sum_d proj_w[e,d]*conv_w[d,i,kk]  (bf16)
//    [192,320):  Pcb[e] = sum_d proj_w[e,d]*conv_b[d]
//    [320,4416): Xbt[b][l][d] = bf16(x[b][d][l])
__global__ __launch_bounds__(256) void k_prep(const float* __restrict__ proj_w,
                                              const float* __restrict__ conv_w,
                                              const float* __restrict__ conv_b,
                                              const float* __restrict__ x,
                                              unsigned short* __restrict__ Mst,
                                              float* __restrict__ Pcb,
                                              unsigned short* __restrict__ Xbt) {
  __shared__ __align__(16) float sm[4160];
  const int bx  = blockIdx.x;
  const int tid = threadIdx.x;

  if (bx < 192) {
    float* Pt = sm;           // [16][68]
    float* Wt = sm + 1088;    // [16][68]
    const int kk = bx >> 6;
    const int t6 = bx & 63;
    const int et = (t6 >> 3) << 6;
    const int it = (t6 & 7) << 6;
    const int tx = tid & 15, ty = tid >> 4;
    const int le = tid & 63, lg = tid >> 6;
    float acc[4][4] = {};
    for (int d0 = 0; d0 < DIM_; d0 += 16) {
      {
        const float4 v = *(const float4*)&proj_w[(size_t)(et + le) * DIM_ + d0 + lg * 4];
        Pt[(lg * 4 + 0) * 68 + le] = v.x;
        Pt[(lg * 4 + 1) * 68 + le] = v.y;
        Pt[(lg * 4 + 2) * 68 + le] = v.z;
        Pt[(lg * 4 + 3) * 68 + le] = v.w;
      }
#pragma unroll
      for (int r = 0; r < 4; ++r) {
        const int dl = r * 4 + lg;
        Wt[dl * 68 + le] = conv_w[(size_t)(d0 + dl) * (DIM_ * 3) + (it + le) * 3 + kk];
      }
      __syncthreads();
#pragma unroll
      for (int dl = 0; dl < 16; ++dl) {
        const float4 pv = *(const float4*)&Pt[dl * 68 + ty * 4];
        const float4 wv = *(const float4*)&Wt[dl * 68 + tx * 4];
        const float pa[4] = {pv.x, pv.y, pv.z, pv.w};
        const float wa[4] = {wv.x, wv.y, wv.z, wv.w};
#pragma unroll
        for (int a = 0; a < 4; ++a)
#pragma unroll
          for (int b = 0; b < 4; ++b) acc[a][b] += pa[a] * wa[b];
      }
      __syncthreads();
    }
#pragma unroll
    for (int a = 0; a < 4; ++a) {
      uint2 pk;
      pk.x = (unsigned int)f2bf(acc[a][0]) | ((unsigned int)f2bf(acc[a][1]) << 16);
      pk.y = (unsigned int)f2bf(acc[a][2]) | ((unsigned int)f2bf(acc[a][3]) << 16);
      *(uint2*)&Mst[(size_t)(kk * DIM_ + et + ty * 4 + a) * DIM_ + it + tx * 4] = pk;
    }
  } else if (bx < 320) {
    const int idx = bx - 192;
    const int e = idx * 4 + (tid >> 6);
    const int j = tid & 63;
    float s = 0.f;
#pragma unroll
    for (int d = j; d < DIM_; d += 64) s += proj_w[(size_t)e * DIM_ + d] * conv_b[d];
#pragma unroll
    for (int off = 32; off > 0; off >>= 1) s += __shfl_down(s, off, 64);
    if (j == 0) Pcb[e] = s;
  } else {
    const int bc = bx - 320;
    const int bb = bc >> 9;
    const int dt = ((bc >> 6) & 7) << 6;
    const int lt = (bc & 63) << 6;
    const int lr  = tid >> 4;
    const int lc4 = (tid & 15) << 2;
#pragma unroll
    for (int r = 0; r < 4; ++r) {
      const int d = r * 16 + lr;
      const float4 v = *(const float4*)&x[((size_t)(bb * DIM_ + dt + d) << 12) + lt + lc4];
      float* row = sm + d * 65 + lc4;
      row[0] = v.x; row[1] = v.y; row[2] = v.z; row[3] = v.w;
    }
    __syncthreads();
#pragma unroll
    for (int rr = 0; rr < 2; ++rr) {
      const int flat = rr * 256 + tid;
      const int l  = flat >> 3;
      const int d8 = (flat & 7) << 3;
      unsigned int w[4];
#pragma unroll
      for (int p = 0; p < 4; ++p) {
        const float f0 = sm[(d8 + 2 * p + 0) * 65 + l];
        const float f1 = sm[(d8 + 2 * p + 1) * 65 + l];
        w[p] = (unsigned int)f2bf(f0) | ((unsigned int)f2bf(f1) << 16);
      }
      uint4 pk; pk.x = w[0]; pk.y = w[1]; pk.z = w[2]; pk.w = w[3];
      *(uint4*)&Xbt[((size_t)(bb * LIN_ + lt + l) << 9) + dt + d8] = pk;
    }
  }
}

// ---------------------------------------------------------------------------
// 2) k_fused — GEMM + AA filter + both biases, out written directly.
//    Per block: M=192 rows (3 kk-planes x 64 e), N=288 computed l-cols
//    (256 output + 16 halo each side), K=512, BK=32 -> 16 kt steps.
//    8 waves (4M x 2N), wave tile 48x144 (3x9 frags), 16x16x32 bf16 MFMA.
//    LDS: 4-deep ring of 32KB slots (A 12K + B 18K + 2K pad) = 128KB;
//    counted vmcnt(12), pre-swizzled gload_lds, raw barriers.
//    Epilogue: acc -> LDS U-tile [192][296] bf16 (unions dead ring), barrier,
//    then 17-tap AA combine from LDS -> out (fp32, coalesced 64B/thread lines).
__global__ __launch_bounds__(512, 2) void k_fused(const unsigned short* __restrict__ Xbt,
                                                  const unsigned short* __restrict__ Mst,
                                                  const float* __restrict__ Pcb,
                                                  const float* __restrict__ aa,
                                                  const float* __restrict__ proj_b,
                                                  float* __restrict__ out) {
  __shared__ __align__(16) char lds[131072];
  const int tid = threadIdx.x;
  const int bid = blockIdx.x;
  // XCD-bijective swizzle (1024 = 8*128); one XCD: 16 ntiles x 8 etiles ->
  // B panels 16*288KB ~= 4.6MB ~ its L2; Mst (1.5MB) shared by all.
  const int wgs   = (bid & 7) * 128 + (bid >> 3);
  const int ntile = wgs >> 3;            // 0..127
  const int etile = wgs & 7;             // 0..7
  const int bb = ntile >> 4;
  const int L0 = (ntile & 15) << 8;      // output l base (256 per tile)
  const int l0g = L0 - 16;               // first computed column
  const int e0 = etile << 6;

  const int wave = tid >> 6;
  const int lane = tid & 63;

  // ---- staging: 32 units x 1KB per slot; wave w -> units w, w+8, w+16, w+24.
  // Units 0-11: A rows m=u*16.. (m = kk*64+e_local, kk=u>>2); 12-29: B rows
  // l=(u-12)*16..; 30,31: dummies (mirror A units 0,1) into the 2KB pad so
  // every wave issues exactly 4 gloads per STAGE -> uniform vmcnt counting.
  const unsigned short* src[4];
  int ldso[4];
#pragma unroll
  for (int i = 0; i < 4; ++i) {
    const int u  = wave + 8 * i;
    const int uu = (u >= 30) ? (u - 30) : u;
    const int rl = lane >> 2;
    const int sl = lane & 3;
    int row;
    const unsigned short* p;
    if (uu < 12) {
      row = uu * 16 + rl;                           // m_local
      const int kk = uu >> 2;
      const int er = e0 + ((uu & 3) << 4) + rl;
      p = Mst + ((long long)(kk * 512 + er) << 9);
    } else {
      const int lr = (uu - 12) * 16 + rl;           // 0..287
      row = lr;
      p = Xbt + ((long long)(bb * LIN_) + (l0g + lr)) * 512;  // may underhang 16 rows (valid ws mem, masked later)
    }
    src[i] = p + ((sl ^ ((row >> 1) & 3)) << 3);    // pre-swizzled source chunk
    ldso[i] = u << 10;
  }

#define STAGE_(kt_, buf_)                              \
  do {                                                 \
    char* base_ = lds + (buf_) * 32768;                \
    gload16(src[0] + (kt_) * 32, base_ + ldso[0]);     \
    gload16(src[1] + (kt_) * 32, base_ + ldso[1]);     \
    gload16(src[2] + (kt_) * 32, base_ + ldso[2]);     \
    gload16(src[3] + (kt_) * 32, base_ + ldso[3]);     \
  } while (0)

  const int wm = wave >> 1;              // 0..3 : 48-row M strip
  const int wn = wave & 1;               // 0..1 : 144-col N half
  const int lrow = lane & 15;
  const int lc   = lane >> 4;            // k-chunk 0..3
  const int asl  = lc ^ ((lrow >> 1) & 3);
  const char* A0 = lds + ((wm * 48 + lrow) * 64 + asl * 16);
  const char* B0 = lds + (12288 + (wn * 144 + lrow) * 64 + asl * 16);

  f32x4 acc[3][9] = {};

  STAGE_(0, 0); STAGE_(1, 1); STAGE_(2, 2);

#pragma unroll 4
  for (int kt = 0; kt < 16; ++kt) {
    if (kt < 13) {
      STAGE_(kt + 3, (kt + 3) & 3);
      asm volatile("s_waitcnt vmcnt(12)" ::: "memory");
    } else if (kt == 13) {
      asm volatile("s_waitcnt vmcnt(8)" ::: "memory");
    } else if (kt == 14) {
      asm volatile("s_waitcnt vmcnt(4)" ::: "memory");
    } else {
      asm volatile("s_waitcnt vmcnt(0)" ::: "memory");
    }
    __builtin_amdgcn_s_barrier();
    __builtin_amdgcn_sched_barrier(0);

    const int bo = (kt & 3) * 32768;
    bf16x8 af[3], bfv[9];
#pragma unroll
    for (int mt = 0; mt < 3; ++mt) af[mt] = *(const bf16x8*)(A0 + bo + mt * 1024);
#pragma unroll
    for (int nt = 0; nt < 9; ++nt) bfv[nt] = *(const bf16x8*)(B0 + bo + nt * 1024);
#pragma unroll
    for (int mt = 0; mt < 3; ++mt)
#pragma unroll
      for (int nt = 0; nt < 9; ++nt)
        // swapped operands: D row = l (quad*4+reg), D col = m (lane&15)
        acc[mt][nt] = __builtin_amdgcn_mfma_f32_16x16x32_bf16(bfv[nt], af[mt],
                                                              acc[mt][nt], 0, 0, 0);
    asm volatile("s_waitcnt lgkmcnt(0)" ::: "memory");
    __builtin_amdgcn_sched_barrier(0);
    __builtin_amdgcn_s_barrier();
  }
#undef STAGE_

  // ---- epilogue A: acc -> LDS U-tile (bf16, stride 296; unions dead ring) ----
  unsigned short* Ut = (unsigned short*)lds;
#pragma unroll
  for (int mt = 0; mt < 3; ++mt) {
    const int m = wm * 48 + mt * 16 + lrow;          // m = kk*64 + e_local
#pragma unroll
    for (int nt = 0; nt < 9; ++nt) {
      const int lcol = wn * 144 + nt * 16 + (lc << 2);
      uint2 pk;
      pk.x = (unsigned int)f2bf(acc[mt][nt][0]) | ((unsigned int)f2bf(acc[mt][nt][1]) << 16);
      pk.y = (unsigned int)f2bf(acc[mt][nt][2]) | ((unsigned int)f2bf(acc[mt][nt][3]) << 16);
      *(uint2*)&Ut[m * 296 + lcol] = pk;
    }
  }
  __syncthreads();

  // ---- epilogue B: AA combine + biases, store out ----
  // thread t: e_local = t>>3, l-chunk base = (t&7)*32 (thread owns a 256B strip)
  const int el  = tid >> 3;
  const int lt0 = (tid & 7) << 5;
  const int e   = e0 + el;
  const float pcb = Pcb[e];
  const float pb  = proj_b[e];
  float sa[17];
#pragma unroll
  for (int j = 0; j < 17; ++j) sa[j] = aa[j];
  const unsigned short* u0r = Ut + (size_t)el * 296;          // kk=0
  const unsigned short* u1r = Ut + (size_t)(64 + el) * 296;   // kk=1
  const unsigned short* u2r = Ut + (size_t)(128 + el) * 296;  // kk=2
  const bool edge = (L0 == 0) || (L0 == 3840);
  float* orow = out + (((size_t)(bb * 512 + e)) << 13) + 2 * (size_t)(L0 + lt0);

#pragma unroll
  for (int cc = 0; cc < 4; ++cc) {
    const int c0 = lt0 + 8 * cc + 12;   // Ut col of E[0]  (c = l - l0g = c0 + j)
    float E[17], O[16];
    if (!edge) {
      // interior: aligned 16B window [c0-4, c0+20) covers all needed cols
      const u16x8 e0v = *(const u16x8*)(u1r + c0 - 4);
      const u16x8 e1v = *(const u16x8*)(u1r + c0 + 4);
      const u16x8 e2v = *(const u16x8*)(u1r + c0 + 12);
      const u16x8 a0v = *(const u16x8*)(u0r + c0 - 4);
      const u16x8 a1v = *(const u16x8*)(u0r + c0 + 4);
      const u16x8 a2v = *(const u16x8*)(u0r + c0 + 12);
      const u16x8 b0v = *(const u16x8*)(u2r + c0 - 4);
      const u16x8 b1v = *(const u16x8*)(u2r + c0 + 4);
      const u16x8 b2v = *(const u16x8*)(u2r + c0 + 12);
      unsigned short ue[24], ua[24], ub[24];
#pragma unroll
      for (int j = 0; j < 8; ++j) {
        ue[j] = e0v[j]; ue[j + 8] = e1v[j]; ue[j + 16] = e2v[j];
        ua[j] = a0v[j]; ua[j + 8] = a1v[j]; ua[j + 16] = a2v[j];
        ub[j] = b0v[j]; ub[j + 8] = b1v[j]; ub[j + 16] = b2v[j];
      }
#pragma unroll
      for (int j = 0; j < 17; ++j) E[j] = bf2f(ue[4 + j]) + pcb;
#pragma unroll
      for (int j = 0; j < 16; ++j) O[j] = bf2f(ua[4 + j]) + pcb + bf2f(ub[5 + j]);
    } else {
      const int lt = L0 + lt0 + 8 * cc;
#pragma unroll
      for (int j = 0; j < 17; ++j) {
        const int l = lt - 4 + j;
        E[j] = (l >= 0 && l < 4096) ? (bf2f(u1r[c0 + j]) + pcb) : 0.f;
      }
#pragma unroll
      for (int j = 0; j < 16; ++j) {
        const int l = lt - 4 + j;
        float v = 0.f;
        if (l >= 0 && l < 4096) {
          v = bf2f(u0r[c0 + j]) + pcb;
          if (l + 1 < 4096) v += bf2f(u2r[c0 + j + 1]);
        }
        O[j] = v;
      }
    }
    float res[16];
#pragma unroll
    for (int t = 0; t < 8; ++t) {
      float se = 0.f, so = 0.f;
#pragma unroll
      for (int q = 0; q <= 8; ++q) {   // even taps
        se += sa[2 * q] * E[t + q];
        so += sa[2 * q] * O[t + q];
      }
#pragma unroll
      for (int q = 0; q < 8; ++q) {    // odd taps
        se += sa[2 * q + 1] * O[t + q];
        so += sa[2 * q + 1] * E[t + q + 1];
      }
      res[2 * t]     = se + pb;
      res[2 * t + 1] = so + pb;
    }
#pragma unroll
    for (int c2 = 0; c2 < 4; ++c2)
      *(float4*)(orow + 16 * cc + 4 * c2) = *(const float4*)&res[4 * c2];
  }
}

// ---------------------------------------------------------------------------
extern "C" void kernel_launch(void* const* d_in, const int* in_sizes, int n_in,
                              void* d_out, int out_size, void* d_ws, size_t ws_size,
                              hipStream_t stream) {
  const float* x      = (const float*)d_in[0];
  const float* conv_w = (const float*)d_in[1];
  const float* conv_b = (const float*)d_in[2];
  const float* aa     = (const float*)d_in[3];
  const float* proj_w = (const float*)d_in[4];
  const float* proj_b = (const float*)d_in[5];
  float* out = (float*)d_out;

  char* ws = (char*)d_ws;
  unsigned short* Mst = (unsigned short*)ws;              //  1,572,864 B
  float*          Pcb = (float*)(ws + 1572864);           //      2,048 B
  unsigned short* Xbt = (unsigned short*)(ws + 1574912);  // 33,554,432 B (tot 35.1MB)

  k_prep<<<dim3(4416, 1, 1), 256, 0, stream>>>(proj_w, conv_w, conv_b, x, Mst, Pcb, Xbt);
  k_fused<<<dim3(1024, 1, 1), 512, 0, stream>>>(Xbt, Mst, Pcb, aa, proj_b, out);
}